// Round 1
// 86.980 us; speedup vs baseline: 1.0295x; 1.0295x over previous
//
#include <hip/hip_runtime.h>

typedef _Float16 h2 __attribute__((ext_vector_type(2)));
typedef unsigned int u32;

// Workspace layout (bytes).
#define OFF_A2   0x100000u  // half2 TILED: [32 slab][32 row][128 hh]  (pre_x)
#define OFF_C2   0x180000u  // same tiling                             (pre_y + b1)

__device__ __forceinline__ u32 pack2(float a, float b) {
  h2 v; v.x = (_Float16)a; v.y = (_Float16)b;
  return __builtin_bit_cast(u32, v);
}
__device__ __forceinline__ h2 as_h2(u32 u) { return __builtin_bit_cast(h2, u); }

__device__ __forceinline__ float fdot2(h2 a, h2 b, float c) {
#if __has_builtin(__builtin_amdgcn_fdot2)
  return __builtin_amdgcn_fdot2(a, b, c, false);
#else
  return (float)a.x * (float)b.x + (float)a.y * (float)b.y + c;
#endif
}
__device__ __forceinline__ h2 relu2(h2 t) {
  h2 z; z.x = (_Float16)0.0f; z.y = (_Float16)0.0f;
  return __builtin_elementwise_max(t, z);  // v_pk_max_f16
}

// K1: pre_x -> A2, pre_y + b1 -> C2, straight from raw f32 inputs (k0 removed).
// 512 blocks (2/CU): mat = b>>8; rt = 32-row tile (0..31); ht = 32-h tile (0..7).
// Stages x-slab (32x128 f32, swizzled quads) + W1 column slice (128x32 f32) in LDS,
// computes in f32 fmac, packs to the tiled half2 layout k2 consumes.
__global__ __launch_bounds__(256) void k1_pre(const float* __restrict__ x,
                                              const float* __restrict__ y,
                                              const float* __restrict__ W1,
                                              const float* __restrict__ b1,
                                              u32* __restrict__ wsu,
                                              float* __restrict__ out) {
  const int b = blockIdx.x, tid = threadIdx.x;
  if (b == 0 && tid == 0) out[0] = 0.0f;   // d_out is poisoned; zero before k2 atomics
  const int mat = b >> 8;                  // 0: x->A2, 1: y->C2
  const int bb = b & 255, ht = bb & 7, rt = bb >> 3;

  __shared__ float4 sx4[32 * 32];          // [row][quad ^ (row&7)]  16 KB
  __shared__ float  sw[128 * 32];          // [k][hcol]              16 KB

  const float* gx = (mat ? y : x) + rt * 32 * 128;
  const float* gw = W1 + mat * (128 * 256) + ht * 32;

  // stage x rows (coalesced float4, XOR-swizzled quad placement)
#pragma unroll
  for (int p = 0; p < 4; ++p) {
    const int idx = p * 256 + tid, r = idx >> 5, q = idx & 31;
    sx4[r * 32 + (q ^ (r & 7))] = *(const float4*)(gx + r * 128 + q * 4);
  }
  // stage W1 column slice (coalesced float4)
#pragma unroll
  for (int p = 0; p < 4; ++p) {
    const int kr = p * 32 + (tid >> 3), c4 = (tid & 7) * 4;
    *(float4*)(sw + kr * 32 + c4) = *(const float4*)(gw + kr * 256 + c4);
  }
  __syncthreads();

  const int tx = tid & 31, ty = tid >> 5;  // r lane, h group (4 h each)
  const int h0 = ty * 4;

  float acc[4];
  if (mat) {
    const float4 bv = *(const float4*)(b1 + ht * 32 + h0);
    acc[0] = bv.x; acc[1] = bv.y; acc[2] = bv.z; acc[3] = bv.w;
  } else {
    acc[0] = acc[1] = acc[2] = acc[3] = 0.0f;
  }

  const float4* xr = sx4 + tx * 32;
  const int swx = tx & 7;
#pragma unroll 8
  for (int k4 = 0; k4 < 32; ++k4) {
    const float4 xv = xr[k4 ^ swx];                       // x[r][4k4..4k4+3]
    const float xs[4] = {xv.x, xv.y, xv.z, xv.w};
#pragma unroll
    for (int kk = 0; kk < 4; ++kk) {                      // w-read: 2 addrs/wave -> broadcast
      const float4 wv = *(const float4*)(sw + (4 * k4 + kk) * 32 + h0);
      acc[0] += xs[kk] * wv.x; acc[1] += xs[kk] * wv.y;
      acc[2] += xs[kk] * wv.z; acc[3] += xs[kk] * wv.w;
    }
  }

  u32* dst = wsu + ((mat ? OFF_C2 : OFF_A2) >> 2) + rt * 4096 + tx * 128;
  const int hh0 = ht * 16 + ty * 2;        // even -> 8B-aligned uint2 store
  uint2 sv;
  sv.x = pack2(acc[0], acc[1]);
  sv.y = pack2(acc[2], acc[3]);
  *(uint2*)(dst + hh0) = sv;
}

// K2: main N^2 kernel. 512 blocks of 64(i) x 32(j) pairs, 256 threads, 4x2/thread.
// vs previous 32x32/2x2: ds_read_b128 per pair-per-g drops 5/4 -> 7/8 (1.43x).
// LDS 48.7 KB -> 2 blocks/CU (8 waves/CU). C-reads are 4-addr/16-way-broadcast
// (conflict-free); A-reads keep the (row>>1)&7 XOR swizzle (2-way = free).
__global__ __launch_bounds__(256) void k2_main(const u32* __restrict__ wsu,
                                               const float* __restrict__ W2g,
                                               const float* __restrict__ B2,
                                               float* __restrict__ out) {
  const int bi = blockIdx.x >> 5, bj = blockIdx.x & 31;  // bi: 64-row i tile (0..15)
  const int tid = threadIdx.x;
  const int tx = tid & 15, TY = tid >> 4;  // j-pair lane, i-quad group

  __shared__ uint4 sA4[32 * 32];           // 16 KB  [jrow][quad^((j>>1)&7)]
  __shared__ uint4 sC4[64 * 32];           // 32 KB  [irow][quad^((i>>2)&7)]
  __shared__ uint4 sW4[32];
  __shared__ float sred[4];
  u32* sW2 = (u32*)sW4;

  {                                        // stage slabs (once)
    const u32* gA = wsu + (OFF_A2 >> 2) + bj * 4096;     // 32 contiguous rows
    const u32* gC = wsu + (OFF_C2 >> 2) + bi * 8192;     // 64 contiguous rows
#pragma unroll
    for (int p = 0; p < 4; ++p) {
      const int idx = p * 256 + tid, j = idx >> 5, q = idx & 31;
      sA4[j * 32 + (q ^ ((j >> 1) & 7))] = *(const uint4*)(gA + j * 128 + q * 4);
    }
#pragma unroll
    for (int p = 0; p < 8; ++p) {
      const int idx = p * 256 + tid, i = idx >> 5, q = idx & 31;
      sC4[i * 32 + (q ^ ((i >> 2) & 7))] = *(const uint4*)(gC + i * 128 + q * 4);
    }
    if (tid < 128) sW2[tid] = pack2(W2g[2 * tid], W2g[2 * tid + 1]);
  }
  __syncthreads();

  const uint4* rA = sA4 + (2 * tx) * 32;   // rows 2tx, 2tx+1
  const uint4* rC = sC4 + (4 * TY) * 32;   // rows 4TY .. 4TY+3
  const int swzA = tx & 7, swzC = TY & 7;

  float acc[4][2] = {{0.0f, 0.0f}, {0.0f, 0.0f}, {0.0f, 0.0f}, {0.0f, 0.0f}};
#pragma unroll 4
  for (int g = 0; g < 32; ++g) {           // 4 hh per step
    const int ga = g ^ swzA, gc = g ^ swzC;
    const uint4 av0 = rA[ga],      av1 = rA[32 + ga];
    const uint4 cv0 = rC[gc],      cv1 = rC[32 + gc];
    const uint4 cv2 = rC[64 + gc], cv3 = rC[96 + gc];
    const uint4 wv  = sW4[g];
    const u32 aa[2][4] = {{av0.x, av0.y, av0.z, av0.w},
                          {av1.x, av1.y, av1.z, av1.w}};
    const u32 cc[4][4] = {{cv0.x, cv0.y, cv0.z, cv0.w},
                          {cv1.x, cv1.y, cv1.z, cv1.w},
                          {cv2.x, cv2.y, cv2.z, cv2.w},
                          {cv3.x, cv3.y, cv3.z, cv3.w}};
    const u32 ww[4] = {wv.x, wv.y, wv.z, wv.w};
#pragma unroll
    for (int q = 0; q < 4; ++q) {
      const h2 w = as_h2(ww[q]);
      const h2 A0 = as_h2(aa[0][q]), A1 = as_h2(aa[1][q]);
#pragma unroll
      for (int m = 0; m < 4; ++m) {
        const h2 C = as_h2(cc[m][q]);
        acc[m][0] = fdot2(relu2(A0 + C), w, acc[m][0]);
        acc[m][1] = fdot2(relu2(A1 + C), w, acc[m][1]);
      }
    }
  }

  // result = (1/n) sum_i (T1_ii + 1) - (1/n^2) sum_ij exp(T1_ij);  T1_ij = d_ij + b2 - 1.
  const float b2 = B2[0];
  float val = 0.0f;
#pragma unroll
  for (int m = 0; m < 4; ++m)
#pragma unroll
    for (int p = 0; p < 2; ++p) val += __expf(acc[m][p] + (b2 - 1.0f));
  val *= -1.0f / 1048576.0f;
  const int i0 = bi * 64 + 4 * TY, j0 = bj * 32 + 2 * tx;
#pragma unroll
  for (int m = 0; m < 4; ++m)
#pragma unroll
    for (int p = 0; p < 2; ++p)
      if (i0 + m == j0 + p) val += (acc[m][p] + b2) * (1.0f / 1024.0f);

#pragma unroll
  for (int off = 32; off > 0; off >>= 1) val += __shfl_down(val, off, 64);
  if ((tid & 63) == 0) sred[tid >> 6] = val;
  __syncthreads();
  if (tid == 0) atomicAdd(out, sred[0] + sred[1] + sred[2] + sred[3]);
}

extern "C" void kernel_launch(void* const* d_in, const int* in_sizes, int n_in,
                              void* d_out, int out_size, void* d_ws, size_t ws_size,
                              hipStream_t stream) {
  const float* x  = (const float*)d_in[0];
  const float* y  = (const float*)d_in[1];
  const float* W1 = (const float*)d_in[2];
  const float* b1 = (const float*)d_in[3];
  const float* W2 = (const float*)d_in[4];
  const float* b2 = (const float*)d_in[5];
  u32* wsu = (u32*)d_ws;

  hipLaunchKernelGGL(k1_pre, dim3(512), dim3(256), 0, stream, x, y, W1, b1, wsu,
                     (float*)d_out);
  hipLaunchKernelGGL(k2_main, dim3(512), dim3(256), 0, stream, wsu, W2, b2,
                     (float*)d_out);
}